// Round 1
// baseline (1798.898 us; speedup 1.0000x reference)
//
#include <hip/hip_runtime.h>
#include <cstddef>

// Problem: D,H,W,C = 10,200,176,64; convs: (s2,p1) -> (s1, p(0,1,1)) -> (s2,p1)
// Intermediates planar-padded fp32: [ci][d][HP=202][WP=192], halos zero.
#define HH 200
#define WW 176
#define HP 202
#define WP 192
#define PLANE (HP * WP)

#define D_IN 10
#define D1 5
#define D2 3
#define D3 2

// ---------------- weight transform: OIDHW -> [tap][ci][co] ----------------
__global__ __launch_bounds__(256) void wtrans_k(const float* __restrict__ src,
                                                float* __restrict__ dst) {
    int idx = blockIdx.x * 256 + threadIdx.x;
    if (idx >= 27 * 64 * 64) return;
    int o = idx & 63;
    int i = (idx >> 6) & 63;
    int tap = idx >> 12;                  // kd*9 + kh*3 + kw
    dst[idx] = src[(o * 64 + i) * 27 + tap];
}

// ---------------- scatter with last-write-wins (np .at[].set semantics) ----
__global__ __launch_bounds__(256) void winner_k(const int* __restrict__ coors,
                                                int* __restrict__ winner, int nvox) {
    int v = blockIdx.x * 256 + threadIdx.x;
    if (v >= nvox) return;
    int d = coors[v * 4 + 1], h = coors[v * 4 + 2], w = coors[v * 4 + 3];
    atomicMax(&winner[(d * HH + h) * WW + w], v + 1);
}

__global__ __launch_bounds__(256) void scatter_k(const float* __restrict__ feat,
                                                 const int* __restrict__ coors,
                                                 const int* __restrict__ winner,
                                                 float* __restrict__ A, int nvox) {
    int v = blockIdx.x * 4 + (threadIdx.x >> 6);
    int ci = threadIdx.x & 63;
    if (v >= nvox) return;
    int d = coors[v * 4 + 1], h = coors[v * 4 + 2], w = coors[v * 4 + 3];
    if (winner[(d * HH + h) * WW + w] != v + 1) return;  // a later voxel owns this cell
    A[((size_t)(ci * D_IN + d) * HP + (h + 1)) * WP + (w + 1)] = feat[v * 64 + ci];
}

// ---------------- direct conv, fused scale+bias+relu ----------------------
// thread = one output (d,h,w); lane spans w (coalesced); 64 fp32 accs (all co).
// Weights [tap][ci][co]: wave-uniform reads -> s_load + SGPR operand on v_fmac.
template <int FINAL>
__global__ __launch_bounds__(256, 4) void conv_k(const float* __restrict__ in,
                                                 float* __restrict__ out,
                                                 const float* __restrict__ wt,
                                                 const float* __restrict__ scale,
                                                 const float* __restrict__ bias,
                                                 int inD, int outD, int strideD, int padD) {
    const int t = threadIdx.x;
    const int w = (blockIdx.x << 6) + (t & 63);
    const int h = (blockIdx.y << 2) + (t >> 6);
    const int d = blockIdx.z;
    const size_t cstride = (size_t)inD * PLANE;  // per-ci plane stride

    float acc[64];
#pragma unroll
    for (int co = 0; co < 64; ++co) acc[co] = 0.f;

    for (int kd = 0; kd < 3; ++kd) {
        const int zd = d * strideD + kd - padD;
        if (zd < 0 || zd >= inD) continue;  // uniform branch
        for (int khw = 0; khw < 9; ++khw) {
            const int kh = khw / 3, kw = khw - 3 * (khw / 3);
            const float* __restrict__ wrow = wt + (kd * 9 + khw) * 4096;
            const float* __restrict__ irow =
                in + ((size_t)zd * HP + (size_t)(h + kh)) * WP + (w + kw);
#pragma unroll 1
            for (int ci = 0; ci < 64; ++ci) {
                const float x = irow[(size_t)ci * cstride];
                const float* __restrict__ wr = wrow + ci * 64;
#pragma unroll
                for (int co = 0; co < 64; ++co) acc[co] = fmaf(x, wr[co], acc[co]);
            }
        }
    }

    if (w < WW) {
#pragma unroll
        for (int co = 0; co < 64; ++co) {
            float v = acc[co] * scale[co] + bias[co];
            v = v > 0.f ? v : 0.f;
            if (FINAL) {
                // final reshape: out channel index = co*outD + d, unpadded HxW
                out[(((size_t)co * outD + d) * HH + h) * WW + w] = v;
            } else {
                out[(((size_t)co * outD + d) * HP + (h + 1)) * WP + (w + 1)] = v;
            }
        }
    }
}

// ---------------- launch ---------------------------------------------------
extern "C" void kernel_launch(void* const* d_in, const int* in_sizes, int n_in,
                              void* d_out, int out_size, void* d_ws, size_t ws_size,
                              hipStream_t stream) {
    const float* feat   = (const float*)d_in[0];
    const int*   coors  = (const int*)d_in[1];
    const float* W1     = (const float*)d_in[3];
    const float* scale1 = (const float*)d_in[4];
    const float* bias1  = (const float*)d_in[5];
    const float* W2     = (const float*)d_in[6];
    const float* scale2 = (const float*)d_in[7];
    const float* bias2  = (const float*)d_in[8];
    const float* W3     = (const float*)d_in[9];
    const float* scale3 = (const float*)d_in[10];
    const float* bias3  = (const float*)d_in[11];
    const int nvox = in_sizes[0] / 64;

    // workspace layout (floats)
    const size_t nA  = (size_t)64 * D_IN * PLANE;   // 24.8M
    const size_t nB  = (size_t)64 * D1 * PLANE;     // 12.4M
    const size_t nC  = (size_t)64 * D2 * PLANE;     // 7.4M
    const size_t nWT = (size_t)27 * 64 * 64;        // 110,592
    float* A   = (float*)d_ws;
    float* B   = A + nA;
    float* C   = B + nB;
    float* wt1 = C + nC;
    float* wt2 = wt1 + nWT;
    float* wt3 = wt2 + nWT;
    int*   win = (int*)(wt3 + nWT);
    const size_t total_bytes = (nA + nB + nC + 3 * nWT) * sizeof(float)
                             + (size_t)D_IN * HH * WW * sizeof(int);

    // zero grids + halos + winner (ws is poisoned 0xAA before every call)
    hipMemsetAsync(d_ws, 0, total_bytes, stream);

    const int nwt_blk = (27 * 64 * 64 + 255) / 256;
    wtrans_k<<<nwt_blk, 256, 0, stream>>>(W1, wt1);
    wtrans_k<<<nwt_blk, 256, 0, stream>>>(W2, wt2);
    wtrans_k<<<nwt_blk, 256, 0, stream>>>(W3, wt3);

    winner_k<<<(nvox + 255) / 256, 256, 0, stream>>>(coors, win, nvox);
    scatter_k<<<(nvox + 3) / 4, 256, 0, stream>>>(feat, coors, win, A, nvox);

    dim3 blk(256);
    // conv1: A(10) -> B(5), stride_d=2, pad_d=1
    conv_k<0><<<dim3(3, 50, D1), blk, 0, stream>>>(A, B, wt1, scale1, bias1, D_IN, D1, 2, 1);
    // conv2: B(5) -> C(3), stride_d=1, pad_d=0
    conv_k<0><<<dim3(3, 50, D2), blk, 0, stream>>>(B, C, wt2, scale2, bias2, D1, D2, 1, 0);
    // conv3: C(3) -> out(2), stride_d=2, pad_d=1, final layout (64*2,200,176)
    conv_k<1><<<dim3(3, 50, D3), blk, 0, stream>>>(C, (float*)d_out, wt3, scale3, bias3, D2, D3, 2, 1);
}

// Round 2
// 449.177 us; speedup vs baseline: 4.0049x; 4.0049x over previous
//
#include <hip/hip_runtime.h>
#include <cstddef>

// D,H,W,C = 10,200,176,64; convs: (s2,p1) -> (s1,p(0,1,1)) -> (s2,p1)
// Activations channels-last fp16: [d][h(+1 halo)][w(+1 halo)][ci], pixel=128B.
#define HH 200
#define WW 176
#define HP 202
#define WP 178
#define D_IN 10
#define D1 5
#define D2 3
#define D3 2

typedef _Float16 h8 __attribute__((ext_vector_type(8)));
typedef float f4 __attribute__((ext_vector_type(4)));

// ---------------- weight transform: OIDHW fp32 -> [tap][co][ci] fp16 -------
__global__ __launch_bounds__(256) void wtrans_k(const float* __restrict__ src,
                                                _Float16* __restrict__ dst) {
    int idx = blockIdx.x * 256 + threadIdx.x;
    if (idx >= 27 * 64 * 64) return;
    int i = idx & 63;            // ci (contiguous in dst)
    int o = (idx >> 6) & 63;     // co
    int tap = idx >> 12;         // kd*9 + kh*3 + kw
    dst[idx] = (_Float16)src[(o * 64 + i) * 27 + tap];
}

// ---------------- scatter, last-write-wins (np .at[].set semantics) --------
__global__ __launch_bounds__(256) void winner_k(const int* __restrict__ coors,
                                                int* __restrict__ winner, int nvox) {
    int v = blockIdx.x * 256 + threadIdx.x;
    if (v >= nvox) return;
    int d = coors[v * 4 + 1], h = coors[v * 4 + 2], w = coors[v * 4 + 3];
    atomicMax(&winner[(d * HH + h) * WW + w], v + 1);
}

__global__ __launch_bounds__(256) void scatter_k(const float* __restrict__ feat,
                                                 const int* __restrict__ coors,
                                                 const int* __restrict__ winner,
                                                 _Float16* __restrict__ A, int nvox) {
    int v = blockIdx.x * 4 + (threadIdx.x >> 6);
    int ci = threadIdx.x & 63;
    if (v >= nvox) return;
    int d = coors[v * 4 + 1], h = coors[v * 4 + 2], w = coors[v * 4 + 3];
    if (winner[(d * HH + h) * WW + w] != v + 1) return;
    A[(((size_t)d * HP + (h + 1)) * WP + (w + 1)) * 64 + ci] = (_Float16)feat[v * 64 + ci];
}

// ---------------- MFMA implicit-GEMM conv, fused scale+bias+relu -----------
// Wave tile: 64 pixels (one h row, 64 consecutive w) x 64 co.
// mfma_f32_16x16x32_f16 layouts (verified, learn_hip m89/m91):
//   A[m=lane&15][k=quad*8+j], B[n=lane&15][k=quad*8+j], D: co=lane&15, pix=quad*4+reg
template <int FINAL>
__global__ __launch_bounds__(256) void conv_mfma_k(
    const _Float16* __restrict__ in, void* __restrict__ outp,
    const _Float16* __restrict__ wt,
    const float* __restrict__ scale, const float* __restrict__ bias,
    int inD, int strideD, int padD) {
    const int lane = threadIdx.x & 63;
    const int wave = threadIdx.x >> 6;
    const int l16 = lane & 15;
    const int quad = lane >> 4;
    const int h = blockIdx.y * 4 + wave;   // one h row per wave
    const int wb = blockIdx.x * 64;        // 0,64,128 (last tile ragged, masked)
    const int d = blockIdx.z;

    f4 acc[4][4];  // [mt][nt]
#pragma unroll
    for (int mt = 0; mt < 4; ++mt)
#pragma unroll
        for (int nt = 0; nt < 4; ++nt) acc[mt][nt] = (f4){0.f, 0.f, 0.f, 0.f};

    const int fragoff = l16 * 64 + quad * 8;  // elements

    for (int kd = 0; kd < 3; ++kd) {
        const int zd = d * strideD + kd - padD;
        if (zd < 0 || zd >= inD) continue;  // wave-uniform
#pragma unroll
        for (int kh = 0; kh < 3; ++kh) {
#pragma unroll
            for (int kw = 0; kw < 3; ++kw) {
                // input row: storage index h+kh (true h-1+kh +1 halo), w+kw
                const _Float16* __restrict__ arow =
                    in + (((size_t)zd * HP + (h + kh)) * WP + (wb + kw)) * 64 + fragoff;
                const _Float16* __restrict__ brow =
                    wt + (size_t)(kd * 9 + kh * 3 + kw) * 4096 + fragoff;
#pragma unroll
                for (int chunk = 0; chunk < 2; ++chunk) {
                    h8 b0 = *(const h8*)(brow + chunk * 32);
                    h8 b1 = *(const h8*)(brow + chunk * 32 + 1024);
                    h8 b2 = *(const h8*)(brow + chunk * 32 + 2048);
                    h8 b3 = *(const h8*)(brow + chunk * 32 + 3072);
#pragma unroll
                    for (int mt = 0; mt < 4; ++mt) {
                        h8 a = *(const h8*)(arow + chunk * 32 + mt * 1024);
                        acc[mt][0] = __builtin_amdgcn_mfma_f32_16x16x32_f16(a, b0, acc[mt][0], 0, 0, 0);
                        acc[mt][1] = __builtin_amdgcn_mfma_f32_16x16x32_f16(a, b1, acc[mt][1], 0, 0, 0);
                        acc[mt][2] = __builtin_amdgcn_mfma_f32_16x16x32_f16(a, b2, acc[mt][2], 0, 0, 0);
                        acc[mt][3] = __builtin_amdgcn_mfma_f32_16x16x32_f16(a, b3, acc[mt][3], 0, 0, 0);
                    }
                }
            }
        }
    }

    // epilogue: scale+bias+relu; D layout: co=l16(+nt*16), pixel=mt*16+quad*4+reg
#pragma unroll
    for (int nt = 0; nt < 4; ++nt) {
        const int co = nt * 16 + l16;
        const float s = scale[co];
        const float bb = bias[co];
#pragma unroll
        for (int mt = 0; mt < 4; ++mt) {
#pragma unroll
            for (int r = 0; r < 4; ++r) {
                const int w = wb + mt * 16 + quad * 4 + r;
                if (w < WW) {
                    float v = acc[mt][nt][r] * s + bb;
                    v = v > 0.f ? v : 0.f;
                    if (FINAL) {
                        ((float*)outp)[(((size_t)d * HH + h) * WW + w) * 64 + co] = v;
                    } else {
                        ((_Float16*)outp)[(((size_t)d * HP + (h + 1)) * WP + (w + 1)) * 64 + co] =
                            (_Float16)v;
                    }
                }
            }
        }
    }
}

// ---------------- final transpose: O[d][h][w][co] -> out[(co*2+d)][h][w] ---
__global__ __launch_bounds__(256) void transpose_k(const float* __restrict__ O,
                                                   float* __restrict__ out) {
    __shared__ float tile[64][65];
    const int wb = blockIdx.x * 64;
    const int h = blockIdx.y;
    const int d = blockIdx.z;
    const int t = threadIdx.x;
    {
        const int co = t & 63;
        const int wl = t >> 6;
#pragma unroll
        for (int p = 0; p < 16; ++p) {
            const int w = wb + wl + p * 4;
            float v = 0.f;
            if (w < WW) v = O[(((size_t)d * HH + h) * WW + w) * 64 + co];
            tile[wl + p * 4][co] = v;
        }
    }
    __syncthreads();
    {
        const int wl = t & 63;
        const int cl = t >> 6;
        const int w = wb + wl;
        if (w < WW) {
#pragma unroll
            for (int p = 0; p < 16; ++p) {
                const int co = cl + p * 4;
                out[(((size_t)(co * 2 + d)) * HH + h) * WW + w] = tile[wl][co];
            }
        }
    }
}

// ---------------- launch ---------------------------------------------------
extern "C" void kernel_launch(void* const* d_in, const int* in_sizes, int n_in,
                              void* d_out, int out_size, void* d_ws, size_t ws_size,
                              hipStream_t stream) {
    const float* feat   = (const float*)d_in[0];
    const int*   coors  = (const int*)d_in[1];
    const float* W1     = (const float*)d_in[3];
    const float* scale1 = (const float*)d_in[4];
    const float* bias1  = (const float*)d_in[5];
    const float* W2     = (const float*)d_in[6];
    const float* scale2 = (const float*)d_in[7];
    const float* bias2  = (const float*)d_in[8];
    const float* W3     = (const float*)d_in[9];
    const float* scale3 = (const float*)d_in[10];
    const float* bias3  = (const float*)d_in[11];
    const int nvox = in_sizes[0] / 64;

    // workspace layout
    const size_t nA1 = (size_t)D_IN * HP * WP * 64;  // fp16 elems
    const size_t nA2 = (size_t)D1 * HP * WP * 64;
    const size_t nA3 = (size_t)D2 * HP * WP * 64;
    const size_t nWin = (size_t)D_IN * HH * WW;      // ints
    const size_t nO = (size_t)D3 * HH * WW * 64;     // fp32 elems
    const size_t nWT = (size_t)27 * 64 * 64;         // fp16 elems

    _Float16* A1 = (_Float16*)d_ws;
    _Float16* A2 = A1 + nA1;
    _Float16* A3 = A2 + nA2;
    int* win = (int*)(A3 + nA3);
    float* O = (float*)(win + nWin);
    _Float16* wt1 = (_Float16*)(O + nO);
    _Float16* wt2 = wt1 + nWT;
    _Float16* wt3 = wt2 + nWT;

    // zero A1..A3 (halos + dense zeros) and winner in one contiguous memset
    const size_t zero_bytes = (nA1 + nA2 + nA3) * sizeof(_Float16) + nWin * sizeof(int);
    hipMemsetAsync(d_ws, 0, zero_bytes, stream);

    const int nwt_blk = (27 * 64 * 64 + 255) / 256;
    wtrans_k<<<nwt_blk, 256, 0, stream>>>(W1, wt1);
    wtrans_k<<<nwt_blk, 256, 0, stream>>>(W2, wt2);
    wtrans_k<<<nwt_blk, 256, 0, stream>>>(W3, wt3);

    winner_k<<<(nvox + 255) / 256, 256, 0, stream>>>(coors, win, nvox);
    scatter_k<<<(nvox + 3) / 4, 256, 0, stream>>>(feat, coors, win, A1, nvox);

    dim3 blk(256);
    // conv1: A1(d=10) -> A2(d=5), stride 2, pad 1
    conv_mfma_k<0><<<dim3(3, 50, D1), blk, 0, stream>>>(A1, A2, wt1, scale1, bias1, D_IN, 2, 1);
    // conv2: A2(5) -> A3(3), stride 1, pad 0 (depth), pad 1 (h,w)
    conv_mfma_k<0><<<dim3(3, 50, D2), blk, 0, stream>>>(A2, A3, wt2, scale2, bias2, D1, 1, 0);
    // conv3: A3(3) -> O(2) channels-last fp32, stride 2, pad 1
    conv_mfma_k<1><<<dim3(3, 50, D3), blk, 0, stream>>>(A3, O, wt3, scale3, bias3, D2, 2, 1);

    // O[d][h][w][co] -> out[(co*2+d)][h][w]
    transpose_k<<<dim3(3, HH, D3), blk, 0, stream>>>(O, (float*)d_out);
}